// Round 10
// baseline (407.442 us; speedup 1.0000x reference)
//
#include <hip/hip_runtime.h>
#include <cstdint>
#include <cstddef>

#define S_LEN 384
#define BATCH 256
#define DIM   192     // HH*WW
#define HID   100
#define G4    400     // 4*HID
#define NCLS  250
#define SEG   64
#define NSEG  6       // S_LEN / SEG

#define LOG2E  1.4426950408889634f
#define LOG2E2 2.8853900817779268f

typedef float    f32x4   __attribute__((ext_vector_type(4)));
typedef short    bf16x8  __attribute__((ext_vector_type(8)));
typedef _Float16 half2_t __attribute__((ext_vector_type(2)));
typedef _Float16 f16x4   __attribute__((ext_vector_type(4)));
typedef _Float16 f16x8   __attribute__((ext_vector_type(8)));

static __device__ __forceinline__ unsigned short f2bf(float f) {
    unsigned u = __float_as_uint(f);
    return (unsigned short)((u + 0x7FFFu + ((u >> 16) & 1u)) >> 16);   // RN
}

// DPP quad_perm cross-lane (VALU ~2cyc; __shfl_xor = ds_bpermute = LDS pipe)
template<int CTRL>
static __device__ __forceinline__ float fdpp(float x) {
    return __int_as_float(
        __builtin_amdgcn_mov_dpp(__float_as_int(x), CTRL, 0xF, 0xF, true));
}
#define DPP_X1 0xB1   // quad_perm [1,0,3,2]  == xor 1
#define DPP_X2 0x4E   // quad_perm [2,3,0,1]  == xor 2

// ---------------------------------------------------------------------------
// Prep (merged): blocks [0,300): Wt_bf[k=400][d=192] = bf16(W[d][k]);
//                blocks [300,382): Ut2[col=400][p=52] half2 of U^T (pad 0)
// ---------------------------------------------------------------------------
__global__ void prep(const float* __restrict__ W, const float* __restrict__ U,
                     unsigned short* __restrict__ Wt, half2_t* __restrict__ Ut2)
{
    int bid = blockIdx.x;
    if (bid < 300) {
        int i = bid * 256 + threadIdx.x;             // 76800 elements
        if (i >= G4 * DIM) return;
        int k = i / DIM, d = i - k * DIM;
        Wt[i] = f2bf(W[(size_t)d * G4 + k]);
    } else {
        int i = (bid - 300) * 256 + threadIdx.x;     // 400*52 = 20800
        if (i >= G4 * 52) return;
        int col = i / 52, p = i - col * 52;
        int j0 = 2 * p, j1 = 2 * p + 1;
        half2_t v;
        v.x = (_Float16)(j0 < HID ? U[(size_t)j0 * G4 + col] : 0.0f);
        v.y = (_Float16)(j1 < HID ? U[(size_t)j1 * G4 + col] : 0.0f);
        Ut2[i] = v;
    }
}

// ---------------------------------------------------------------------------
// FUSED kernel (round 10). 256 blocks x 576 threads (9 waves), 1 block/CU.
//   Waves 0-6 (t<448): the r8 scan consumer, UNCHANGED datapath (fdot2 +
//     DPP quad reduce/gather), except z comes from LDS zb instead of global.
//   Waves 7-8 (t>=448): MFMA producer. While consumers scan segment g, the
//     producers compute pre for segment g+1 (64 steps x 400 gates) with
//     mfma_f32_16x16x32_bf16 directly into zb[(g+1)&1]:
//       A[m=lane&15=s-row][k=q*8+j] from x (fp32->bf16 inline)
//       B[k][n] = Wt rows (k-major, L2-resident)  D: col=k, rows=4 consec s
//     Producer work (~3-5k cyc/segment/wave) hides under the consumer's
//     ~70k-cyc segment (m114: MFMA+VALU pipes co-schedule across waves);
//     split into 4 mt-chunks (one per 8-step group) so producers never
//     arrive late at a barrier. This DELETES the separate gemm kernel and
//     the 78MB preh write + 40MB fetch (rounds 6-9: ~148-221us residue).
//   zb rows padded 64->72 f16 (144B): 16B-aligned b128 consumer reads,
//     <=2-way producer write conflicts. LDS: 2*57.6KB + h bufs = ~117KB.
//   Barriers: every thread executes 1 + 6*64 + 1 = 386, all at top level.
// ---------------------------------------------------------------------------
__global__ __launch_bounds__(576, 1)
void lstm_fused(const float* __restrict__ x, const unsigned short* __restrict__ Wt,
                const half2_t* __restrict__ Ut2, const float* __restrict__ bias,
                const float* __restrict__ Wd, const float* __restrict__ bd,
                float* __restrict__ out)
{
    __shared__ _Float16 zb[2][G4 * 72];      // [k][s] f16, s-pad 64->72
    __shared__ _Float16 h2[2][160];          // 4 slices x 40 f16 (26 used)
    __shared__ __align__(16) float hf32[HID];

    const int b = blockIdx.x;
    const int t = threadIdx.x;
    const bool cons = (t < 448);

    // consumer ids
    const int jg = t & 3;
    const int nr = t >> 2;
    const int n  = (nr < HID) ? nr : HID - 1;
    const bool active = cons && (nr < HID);
    const int col  = jg * HID + n;
    const int slot = (n / 26) * 40 + (n % 26);

    // producer ids
    const int pt = t - 448;                  // 0..127 on producers
    const int plane = pt & 63;
    const int pw = pt >> 6;                  // producer wave 0/1
    const int pm = plane & 15, pq = plane >> 4;
    const int nt0 = pw ? 13 : 0;
    const int ntN = pw ? 12 : 13;            // 25 k-tiles split 13/12

    // one mt-chunk of producing segment `seg` into zb[buf]
    auto produce_mt = [&](int seg, int buf, int mt) {
        const float* __restrict__ xr =
            x + ((size_t)b * S_LEN + seg * SEG + mt * 16 + pm) * DIM + pq * 8;
        bf16x8 afr[6];
#pragma unroll
        for (int dc = 0; dc < 6; ++dc) {
            float4 a0 = *(const float4*)(xr + dc * 32);
            float4 a1 = *(const float4*)(xr + dc * 32 + 4);
            bf16x8 af;
            af[0] = (short)f2bf(a0.x); af[1] = (short)f2bf(a0.y);
            af[2] = (short)f2bf(a0.z); af[3] = (short)f2bf(a0.w);
            af[4] = (short)f2bf(a1.x); af[5] = (short)f2bf(a1.y);
            af[6] = (short)f2bf(a1.z); af[7] = (short)f2bf(a1.w);
            afr[dc] = af;
        }
        for (int u = 0; u < ntN; ++u) {
            const int kg = (nt0 + u) * 16 + pm;          // gate column 0..399
            const unsigned short* __restrict__ wp = Wt + (size_t)kg * DIM + pq * 8;
            f32x4 acc = (f32x4){0.f, 0.f, 0.f, 0.f};
#pragma unroll
            for (int dc = 0; dc < 6; ++dc) {
                bf16x8 bf = *(const bf16x8*)(wp + dc * 32);
                acc = __builtin_amdgcn_mfma_f32_16x16x32_bf16(afr[dc], bf, acc, 0, 0, 0);
            }
            const float bv = bias[kg];
            f16x4 st;
            st[0] = (_Float16)(acc[0] + bv);
            st[1] = (_Float16)(acc[1] + bv);
            st[2] = (_Float16)(acc[2] + bv);
            st[3] = (_Float16)(acc[3] + bv);
            // D rows = pq*4+reg = 4 consecutive s within the 16-row m-tile
            *(f16x4*)&zb[buf][kg * 72 + mt * 16 + pq * 4] = st;
        }
    };

    half2_t Uc[4][13];
    float c = 0.f;
    float hn_last = 0.f;

    if (cons) {
        // Uc[i] = fragments of gate (jg XOR i), j-slice jg (13 j-pairs)
#pragma unroll
        for (int i = 0; i < 4; ++i) {
            const int qq = jg ^ i;
            const half2_t* up = Ut2 + (size_t)(qq * HID + n) * 52 + 13 * jg;
#pragma unroll
            for (int r = 0; r < 13; ++r) Uc[i][r] = up[r];
        }
        if (t < 320) ((_Float16*)h2)[t] = (_Float16)0.f;
    } else {
        // prime segment 0 (consumers idle-wait at the barrier below)
#pragma unroll
        for (int mt = 0; mt < 4; ++mt) produce_mt(0, 0, mt);
    }
    __syncthreads();                         // h2 zeroed + zb[0] ready

    const float scale = (jg == 2) ? -LOG2E2 : -LOG2E;
    const float Aact  = (jg == 2) ? 2.0f : 1.0f;
    const float Bact  = (jg == 2) ? -1.0f : 0.0f;

    for (int seg = 0; seg < NSEG; ++seg) {
        const _Float16* __restrict__ zrow = &zb[seg & 1][col * 72];
        for (int k8g = 0; k8g < SEG / 8; ++k8g) {
            // producer: one mt-chunk of segment seg+1 per 8-step group
            if (!cons && seg + 1 < NSEG && k8g < 4)
                produce_mt(seg + 1, (seg + 1) & 1, k8g);

            f16x8 zv;
            if (cons) zv = *(const f16x8*)(zrow + k8g * 8);
#pragma unroll
            for (int kk = 0; kk < 8; ++kk) {
                if (cons) {
                    const int cur = kk & 1;
                    const _Float16* hb = &h2[cur][jg * 40];
                    f16x8  hA  = *(const f16x8*)hb;
                    f16x8  hB  = *(const f16x8*)(hb + 8);
                    f16x8  hC  = *(const f16x8*)(hb + 16);
                    half2_t hD = *(const half2_t*)(hb + 24);
                    half2_t hp[13];
                    hp[0]  = __builtin_shufflevector(hA, hA, 0, 1);
                    hp[1]  = __builtin_shufflevector(hA, hA, 2, 3);
                    hp[2]  = __builtin_shufflevector(hA, hA, 4, 5);
                    hp[3]  = __builtin_shufflevector(hA, hA, 6, 7);
                    hp[4]  = __builtin_shufflevector(hB, hB, 0, 1);
                    hp[5]  = __builtin_shufflevector(hB, hB, 2, 3);
                    hp[6]  = __builtin_shufflevector(hB, hB, 4, 5);
                    hp[7]  = __builtin_shufflevector(hB, hB, 6, 7);
                    hp[8]  = __builtin_shufflevector(hC, hC, 0, 1);
                    hp[9]  = __builtin_shufflevector(hC, hC, 2, 3);
                    hp[10] = __builtin_shufflevector(hC, hC, 4, 5);
                    hp[11] = __builtin_shufflevector(hC, hC, 6, 7);
                    hp[12] = hD;

                    float p0 = 0.f, p1 = 0.f, p2 = 0.f, p3 = 0.f;
#pragma unroll
                    for (int r = 0; r < 13; ++r) {
                        p0 = __builtin_amdgcn_fdot2(Uc[0][r], hp[r], p0, false);
                        p1 = __builtin_amdgcn_fdot2(Uc[1][r], hp[r], p1, false);
                        p2 = __builtin_amdgcn_fdot2(Uc[2][r], hp[r], p2, false);
                        p3 = __builtin_amdgcn_fdot2(Uc[3][r], hp[r], p3, false);
                    }
                    // XOR-permuted transpose-reduce: 3 DPP + 3 add, no selects
                    float r0 = p0 + fdpp<DPP_X1>(p1);
                    float r1 = p2 + fdpp<DPP_X1>(p3);
                    float a  = r0 + fdpp<DPP_X2>(r1) + (float)zv[kk];

                    float e = __builtin_amdgcn_exp2f(scale * a);
                    float v = fmaf(Aact, __builtin_amdgcn_rcpf(1.0f + e), Bact);

                    float q1 = fdpp<DPP_X1>(v);   // gate jg^1 -> f on jg=0
                    float q2 = fdpp<DPP_X2>(v);   // gate jg^2 -> g on jg=0
                    float q3 = fdpp<DPP_X2>(q1);  // gate jg^3 -> o on jg=0

                    c = fmaf(q1, c, v * q2);      // f*c + i*g  (valid on jg=0)
                    float ec = __builtin_amdgcn_exp2f(-LOG2E2 * c);
                    float tc = fmaf(2.0f, __builtin_amdgcn_rcpf(1.0f + ec), -1.0f);
                    float hn = q3 * tc;           // o * tanh(c) (valid on jg=0)
                    if (jg == 0 && active) h2[cur ^ 1][slot] = (_Float16)hn;
                    hn_last = hn;
                }
                __syncthreads();
            }
        }
    }

    if (active && jg == 0) hf32[n] = hn_last;
    __syncthreads();
    if (t < NCLS) {
        float acc2 = bd[t];
        const float4* h4 = (const float4*)hf32;
#pragma unroll 5
        for (int j4 = 0; j4 < 25; ++j4) {
            float4 hv = h4[j4];
            acc2 = fmaf(hv.x, Wd[(size_t)(4 * j4 + 0) * NCLS + t], acc2);
            acc2 = fmaf(hv.y, Wd[(size_t)(4 * j4 + 1) * NCLS + t], acc2);
            acc2 = fmaf(hv.z, Wd[(size_t)(4 * j4 + 2) * NCLS + t], acc2);
            acc2 = fmaf(hv.w, Wd[(size_t)(4 * j4 + 3) * NCLS + t], acc2);
        }
        out[(size_t)b * NCLS + t] = acc2;
    }
}

// ---------------------------------------------------------------------------
extern "C" void kernel_launch(void* const* d_in, const int* in_sizes, int n_in,
                              void* d_out, int out_size, void* d_ws, size_t ws_size,
                              hipStream_t stream)
{
    const float* x    = (const float*)d_in[0];
    const float* W    = (const float*)d_in[1];
    const float* U    = (const float*)d_in[2];
    const float* bias = (const float*)d_in[3];
    const float* Wd   = (const float*)d_in[4];
    const float* bd   = (const float*)d_in[5];
    float* out = (float*)d_out;

    // ws (dwords): [Ut2 20800][Wt_bf 38400]  (~237KB; no pre, no state)
    unsigned int* wsb = (unsigned int*)d_ws;
    half2_t*        Ut2 = (half2_t*)wsb;
    unsigned short* Wt  = (unsigned short*)(wsb + 20800);

    prep<<<382, 256, 0, stream>>>(W, U, Wt, Ut2);
    lstm_fused<<<BATCH, 576, 0, stream>>>(x, Wt, Ut2, bias, Wd, bd, out);
}

// Round 11
// 385.001 us; speedup vs baseline: 1.0583x; 1.0583x over previous
//
#include <hip/hip_runtime.h>
#include <cstdint>
#include <cstddef>

#define S_LEN 384
#define BATCH 256
#define DIM   192     // HH*WW
#define HID   100
#define G4    400     // 4*HID
#define NCLS  250
#define SEG   64
#define NSEG  6       // S_LEN / SEG
#define ZPAD  68      // zb row stride in f16: 136B = 34 dwords -> 2-way = free

#define LOG2E  1.4426950408889634f
#define LOG2E2 2.8853900817779268f

typedef float    f32x4   __attribute__((ext_vector_type(4)));
typedef short    bf16x8  __attribute__((ext_vector_type(8)));
typedef _Float16 half2_t __attribute__((ext_vector_type(2)));
typedef _Float16 f16x4   __attribute__((ext_vector_type(4)));
typedef _Float16 f16x8   __attribute__((ext_vector_type(8)));

static __device__ __forceinline__ unsigned short f2bf(float f) {
    unsigned u = __float_as_uint(f);
    return (unsigned short)((u + 0x7FFFu + ((u >> 16) & 1u)) >> 16);   // RN
}

// DPP quad_perm cross-lane (VALU ~2cyc; __shfl_xor = ds_bpermute = LDS pipe)
template<int CTRL>
static __device__ __forceinline__ float fdpp(float x) {
    return __int_as_float(
        __builtin_amdgcn_mov_dpp(__float_as_int(x), CTRL, 0xF, 0xF, true));
}
#define DPP_X1 0xB1   // quad_perm [1,0,3,2]  == xor 1
#define DPP_X2 0x4E   // quad_perm [2,3,0,1]  == xor 2

// ---------------------------------------------------------------------------
// Prep (merged): blocks [0,300): Wt_bf[k=400][d=192] = bf16(W[d][k]);
//                blocks [300,382): Ut2[col=400][p=52] half2 of U^T (pad 0)
// ---------------------------------------------------------------------------
__global__ void prep(const float* __restrict__ W, const float* __restrict__ U,
                     unsigned short* __restrict__ Wt, half2_t* __restrict__ Ut2)
{
    int bid = blockIdx.x;
    if (bid < 300) {
        int i = bid * 256 + threadIdx.x;             // 76800 elements
        if (i >= G4 * DIM) return;
        int k = i / DIM, d = i - k * DIM;
        Wt[i] = f2bf(W[(size_t)d * G4 + k]);
    } else {
        int i = (bid - 300) * 256 + threadIdx.x;     // 400*52 = 20800
        if (i >= G4 * 52) return;
        int col = i / 52, p = i - col * 52;
        int j0 = 2 * p, j1 = 2 * p + 1;
        half2_t v;
        v.x = (_Float16)(j0 < HID ? U[(size_t)j0 * G4 + col] : 0.0f);
        v.y = (_Float16)(j1 < HID ? U[(size_t)j1 * G4 + col] : 0.0f);
        Ut2[i] = v;
    }
}

// ---------------------------------------------------------------------------
// FUSED kernel (round 11). 256 blocks x 576 threads (9 waves), 1 block/CU.
//   Waves 0-6: r8 scan consumer (fdot2 + DPP), z from LDS zb.
//   Waves 7-8: MFMA producer for segment seg+1 into zb[(seg+1)&1].
//   ROUND-11 FIX vs r10 (335us, sum-not-max): producer work quantum is now
//   ONE k-tile per barrier interval (~250-500 cyc << 1140-cyc consumer step).
//   Each mt-chunk (16 s-rows) spans TWO 8-step groups = 16 intervals:
//     interval 0: x-fragment loads (afr);  intervals 1..13: one tile each.
//   Loads are self-contained per interval, so the pre-barrier vmcnt drain
//   costs <=~400 cyc -- inside the step budget -> producer fully hidden.
//   zb pad 64->68 f16 (34 dwords): 2-way bank aliasing = free (r10's 72
//   -> 36 dwords -> 8-way, 614k conflicts).
// ---------------------------------------------------------------------------
__global__ __launch_bounds__(576, 1)
void lstm_fused(const float* __restrict__ x, const unsigned short* __restrict__ Wt,
                const half2_t* __restrict__ Ut2, const float* __restrict__ bias,
                const float* __restrict__ Wd, const float* __restrict__ bd,
                float* __restrict__ out)
{
    __shared__ _Float16 zb[2][G4 * ZPAD];    // [k][s] f16, s-pad 64->68
    __shared__ _Float16 h2[2][160];          // 4 slices x 40 f16 (26 used)
    __shared__ __align__(16) float hf32[HID];

    const int b = blockIdx.x;
    const int t = threadIdx.x;
    const bool cons = (t < 448);

    // consumer ids
    const int jg = t & 3;
    const int nr = t >> 2;
    const int n  = (nr < HID) ? nr : HID - 1;
    const bool active = cons && (nr < HID);
    const int col  = jg * HID + n;
    const int slot = (n / 26) * 40 + (n % 26);

    // producer ids
    const int pt = t - 448;                  // 0..127 on producers
    const int plane = pt & 63;
    const int pw = pt >> 6;                  // producer wave 0/1
    const int pm = plane & 15, pq = plane >> 4;
    const int nt0 = pw ? 13 : 0;
    const int ntN = pw ? 12 : 13;            // 25 k-tiles split 13/12

    bf16x8 afr[6];                           // producer A fragments (one mt)
    float  bvr[13];                          // producer bias regs

    auto load_afr = [&](int seg, int mt) {
        const float* __restrict__ xr =
            x + ((size_t)b * S_LEN + seg * SEG + mt * 16 + pm) * DIM + pq * 8;
#pragma unroll
        for (int dc = 0; dc < 6; ++dc) {
            float4 a0 = *(const float4*)(xr + dc * 32);
            float4 a1 = *(const float4*)(xr + dc * 32 + 4);
            bf16x8 af;
            af[0] = (short)f2bf(a0.x); af[1] = (short)f2bf(a0.y);
            af[2] = (short)f2bf(a0.z); af[3] = (short)f2bf(a0.w);
            af[4] = (short)f2bf(a1.x); af[5] = (short)f2bf(a1.y);
            af[6] = (short)f2bf(a1.z); af[7] = (short)f2bf(a1.w);
            afr[dc] = af;
        }
    };
    auto produce_tile = [&](int buf, int mt, int u) {
        const int kg = (nt0 + u) * 16 + pm;          // gate column 0..399
        const unsigned short* __restrict__ wp = Wt + (size_t)kg * DIM + pq * 8;
        f32x4 acc = (f32x4){0.f, 0.f, 0.f, 0.f};
#pragma unroll
        for (int dc = 0; dc < 6; ++dc) {
            bf16x8 bf = *(const bf16x8*)(wp + dc * 32);
            acc = __builtin_amdgcn_mfma_f32_16x16x32_bf16(afr[dc], bf, acc, 0, 0, 0);
        }
        const float bv = bvr[u];
        f16x4 st;
        st[0] = (_Float16)(acc[0] + bv);
        st[1] = (_Float16)(acc[1] + bv);
        st[2] = (_Float16)(acc[2] + bv);
        st[3] = (_Float16)(acc[3] + bv);
        // D rows = pq*4+reg = 4 consecutive s within the 16-row m-tile
        *(f16x4*)&zb[buf][kg * ZPAD + mt * 16 + pq * 4] = st;
    };

    half2_t Uc[4][13];
    float c = 0.f;
    float hn_last = 0.f;

    if (cons) {
        // Uc[i] = fragments of gate (jg XOR i), j-slice jg (13 j-pairs)
#pragma unroll
        for (int i = 0; i < 4; ++i) {
            const int qq = jg ^ i;
            const half2_t* up = Ut2 + (size_t)(qq * HID + n) * 52 + 13 * jg;
#pragma unroll
            for (int r = 0; r < 13; ++r) Uc[i][r] = up[r];
        }
        if (t < 320) ((_Float16*)h2)[t] = (_Float16)0.f;
    } else {
#pragma unroll
        for (int u = 0; u < 13; ++u)
            bvr[u] = (u < ntN) ? bias[(nt0 + u) * 16 + pm] : 0.f;
        // prime segment 0 (consumers idle-wait at the barrier below)
        for (int mt = 0; mt < 4; ++mt) {
            load_afr(0, mt);
            for (int u = 0; u < ntN; ++u) produce_tile(0, mt, u);
        }
    }
    __syncthreads();                         // h2 zeroed + zb[0] ready

    const float scale = (jg == 2) ? -LOG2E2 : -LOG2E;
    const float Aact  = (jg == 2) ? 2.0f : 1.0f;
    const float Bact  = (jg == 2) ? -1.0f : 0.0f;

    for (int seg = 0; seg < NSEG; ++seg) {
        const _Float16* __restrict__ zrow = &zb[seg & 1][col * ZPAD];
        const int pbuf = (seg + 1) & 1;
        const bool pgo = (seg + 1 < NSEG);
        for (int k8g = 0; k8g < SEG / 8; ++k8g) {
            const int mt = k8g >> 1;         // mt-chunk spans 2 groups
            f16x4 zva, zvb;
            if (cons) {                      // 8B loads: 8-aligned for all cols
                zva = *(const f16x4*)(zrow + k8g * 8);
                zvb = *(const f16x4*)(zrow + k8g * 8 + 4);
            }
#pragma unroll
            for (int kk = 0; kk < 8; ++kk) {
                if (cons) {
                    const int cur = kk & 1;
                    const _Float16* hb = &h2[cur][jg * 40];
                    f16x8  hA  = *(const f16x8*)hb;
                    f16x8  hB  = *(const f16x8*)(hb + 8);
                    f16x8  hC  = *(const f16x8*)(hb + 16);
                    half2_t hD = *(const half2_t*)(hb + 24);
                    half2_t hp[13];
                    hp[0]  = __builtin_shufflevector(hA, hA, 0, 1);
                    hp[1]  = __builtin_shufflevector(hA, hA, 2, 3);
                    hp[2]  = __builtin_shufflevector(hA, hA, 4, 5);
                    hp[3]  = __builtin_shufflevector(hA, hA, 6, 7);
                    hp[4]  = __builtin_shufflevector(hB, hB, 0, 1);
                    hp[5]  = __builtin_shufflevector(hB, hB, 2, 3);
                    hp[6]  = __builtin_shufflevector(hB, hB, 4, 5);
                    hp[7]  = __builtin_shufflevector(hB, hB, 6, 7);
                    hp[8]  = __builtin_shufflevector(hC, hC, 0, 1);
                    hp[9]  = __builtin_shufflevector(hC, hC, 2, 3);
                    hp[10] = __builtin_shufflevector(hC, hC, 4, 5);
                    hp[11] = __builtin_shufflevector(hC, hC, 6, 7);
                    hp[12] = hD;

                    float p0 = 0.f, p1 = 0.f, p2 = 0.f, p3 = 0.f;
#pragma unroll
                    for (int r = 0; r < 13; ++r) {
                        p0 = __builtin_amdgcn_fdot2(Uc[0][r], hp[r], p0, false);
                        p1 = __builtin_amdgcn_fdot2(Uc[1][r], hp[r], p1, false);
                        p2 = __builtin_amdgcn_fdot2(Uc[2][r], hp[r], p2, false);
                        p3 = __builtin_amdgcn_fdot2(Uc[3][r], hp[r], p3, false);
                    }
                    // XOR-permuted transpose-reduce: 3 DPP + 3 add, no selects
                    float r0 = p0 + fdpp<DPP_X1>(p1);
                    float r1 = p2 + fdpp<DPP_X1>(p3);
                    float zk = (kk < 4) ? (float)zva[kk] : (float)zvb[kk - 4];
                    float a  = r0 + fdpp<DPP_X2>(r1) + zk;

                    float e = __builtin_amdgcn_exp2f(scale * a);
                    float v = fmaf(Aact, __builtin_amdgcn_rcpf(1.0f + e), Bact);

                    float q1 = fdpp<DPP_X1>(v);   // gate jg^1 -> f on jg=0
                    float q2 = fdpp<DPP_X2>(v);   // gate jg^2 -> g on jg=0
                    float q3 = fdpp<DPP_X2>(q1);  // gate jg^3 -> o on jg=0

                    c = fmaf(q1, c, v * q2);      // f*c + i*g  (valid on jg=0)
                    float ec = __builtin_amdgcn_exp2f(-LOG2E2 * c);
                    float tc = fmaf(2.0f, __builtin_amdgcn_rcpf(1.0f + ec), -1.0f);
                    float hn = q3 * tc;           // o * tanh(c) (valid on jg=0)
                    if (jg == 0 && active) h2[cur ^ 1][slot] = (_Float16)hn;
                    hn_last = hn;
                } else if (pgo) {
                    // one small quantum per barrier interval (the r10 fix):
                    // kk_g 0 = afr loads; kk_g 1..13 = one k-tile each
                    const int kk_g = ((k8g & 1) << 3) + kk;   // 0..15
                    if (kk_g == 0)           load_afr(seg + 1, mt);
                    else if (kk_g - 1 < ntN) produce_tile(pbuf, mt, kk_g - 1);
                }
                __syncthreads();
            }
        }
    }

    if (active && jg == 0) hf32[n] = hn_last;
    __syncthreads();
    if (t < NCLS) {
        float acc2 = bd[t];
        const float4* h4 = (const float4*)hf32;
#pragma unroll 5
        for (int j4 = 0; j4 < 25; ++j4) {
            float4 hv = h4[j4];
            acc2 = fmaf(hv.x, Wd[(size_t)(4 * j4 + 0) * NCLS + t], acc2);
            acc2 = fmaf(hv.y, Wd[(size_t)(4 * j4 + 1) * NCLS + t], acc2);
            acc2 = fmaf(hv.z, Wd[(size_t)(4 * j4 + 2) * NCLS + t], acc2);
            acc2 = fmaf(hv.w, Wd[(size_t)(4 * j4 + 3) * NCLS + t], acc2);
        }
        out[(size_t)b * NCLS + t] = acc2;
    }
}

// ---------------------------------------------------------------------------
extern "C" void kernel_launch(void* const* d_in, const int* in_sizes, int n_in,
                              void* d_out, int out_size, void* d_ws, size_t ws_size,
                              hipStream_t stream)
{
    const float* x    = (const float*)d_in[0];
    const float* W    = (const float*)d_in[1];
    const float* U    = (const float*)d_in[2];
    const float* bias = (const float*)d_in[3];
    const float* Wd   = (const float*)d_in[4];
    const float* bd   = (const float*)d_in[5];
    float* out = (float*)d_out;

    // ws (dwords): [Ut2 20800][Wt_bf 38400]  (~237KB; no pre, no state)
    unsigned int* wsb = (unsigned int*)d_ws;
    half2_t*        Ut2 = (half2_t*)wsb;
    unsigned short* Wt  = (unsigned short*)(wsb + 20800);

    prep<<<382, 256, 0, stream>>>(W, U, Wt, Ut2);
    lstm_fused<<<BATCH, 576, 0, stream>>>(x, Wt, Ut2, bias, Wd, bd, out);
}

// Round 13
// 321.766 us; speedup vs baseline: 1.2663x; 1.1965x over previous
//
#include <hip/hip_runtime.h>
#include <cstdint>
#include <cstddef>

#define S_LEN 384
#define BATCH 256
#define DIM   192     // HH*WW
#define HID   100
#define G4    400     // 4*HID
#define NCLS  250

#define LOG2E  1.4426950408889634f
#define LOG2E2 2.8853900817779268f

typedef float    f32x4   __attribute__((ext_vector_type(4)));
typedef short    bf16x8  __attribute__((ext_vector_type(8)));
typedef _Float16 half2_t __attribute__((ext_vector_type(2)));
typedef _Float16 f16x4   __attribute__((ext_vector_type(4)));
typedef _Float16 f16x8   __attribute__((ext_vector_type(8)));

static __device__ __forceinline__ unsigned short f2bf(float f) {
    unsigned u = __float_as_uint(f);
    return (unsigned short)((u + 0x7FFFu + ((u >> 16) & 1u)) >> 16);   // RN
}

// DPP quad_perm cross-lane (VALU ~2cyc)
template<int CTRL>
static __device__ __forceinline__ float fdpp(float x) {
    return __int_as_float(
        __builtin_amdgcn_mov_dpp(__float_as_int(x), CTRL, 0xF, 0xF, true));
}
#define DPP_X1 0xB1   // quad_perm [1,0,3,2]  == xor 1

// ---------------------------------------------------------------------------
// Prep: blocks [0,300): Wt_bf[k=400][d=192] = bf16(W[d][k]);
//       blocks [300,382): Ut2b — per-thread-(n,p) U fragments for the
//       256-thr scan:  Ut2b[((n*2+p)*4+gi)*26 + r] = half2 of
//       U[j0][col], U[j0+1][col] with j0 = 52p + 2r and gate order
//       gi -> gate [2p, 2p+1, 2-2p, 3-2p] (XOR pairing for the DPP reduce).
// ---------------------------------------------------------------------------
__global__ void prep(const float* __restrict__ W, const float* __restrict__ U,
                     unsigned short* __restrict__ Wt, half2_t* __restrict__ Ut2b)
{
    int bid = blockIdx.x;
    if (bid < 300) {
        int i = bid * 256 + threadIdx.x;             // 76800 elements
        if (i >= G4 * DIM) return;
        int k = i / DIM, d = i - k * DIM;
        Wt[i] = f2bf(W[(size_t)d * G4 + k]);
    } else {
        int i = (bid - 300) * 256 + threadIdx.x;     // 100*2*4*26 = 20800
        if (i >= 20800) return;
        int n    = i / 208;
        int rem  = i - n * 208;
        int p    = rem / 104;
        int rem2 = rem - p * 104;
        int gi   = rem2 / 26;
        int r    = rem2 - gi * 26;
        int g    = (gi < 2) ? (2 * p + gi) : (2 * (1 - p) + (gi - 2));
        int col  = g * HID + n;
        int j0   = 52 * p + 2 * r;
        half2_t v;
        v.x = (_Float16)(j0     < HID ? U[(size_t)j0       * G4 + col] : 0.0f);
        v.y = (_Float16)(j0 + 1 < HID ? U[(size_t)(j0 + 1) * G4 + col] : 0.0f);
        Ut2b[i] = v;
    }
}

// ---------------------------------------------------------------------------
// Kernel 1: bf16 MFMA GEMM (byte-identical to round 8's verified kernel).
//   pre[b][k][s] = x[b][s][:].W[:][k] + bias[k], stored f16.
// ---------------------------------------------------------------------------
__global__ __launch_bounds__(256, 2)
void gemm_pre(const float* __restrict__ x, const unsigned short* __restrict__ Wt,
              const float* __restrict__ bias, _Float16* __restrict__ preh,
              int s_start, int chunk)
{
    __shared__ unsigned int xs[64 * 100];    // rows: 200 bf16 (192 + 8 pad)
    __shared__ unsigned int wsh[400 * 20];   // rows: 40 bf16 (32 + 8 pad)

    const int t    = threadIdx.x;
    const int lane = t & 63;
    const int w    = t >> 6;
    const int nsb  = chunk >> 6;
    const int b    = blockIdx.x / nsb;
    const int sblk = blockIdx.x - b * nsb;
    const float* __restrict__ xb = x + ((size_t)b * S_LEN + s_start + sblk * 64) * DIM;

#pragma unroll
    for (int r = 0; r < 12; ++r) {
        int i = t + r * 256;                 // 3072 float4 = 64 rows x 48
        int row = i / 48, c4 = i - row * 48;
        float4 v = ((const float4*)(xb + (size_t)row * DIM))[c4];
        xs[row * 100 + c4 * 2]     = (unsigned)f2bf(v.x) | ((unsigned)f2bf(v.y) << 16);
        xs[row * 100 + c4 * 2 + 1] = (unsigned)f2bf(v.z) | ((unsigned)f2bf(v.w) << 16);
    }

    const int m = lane & 15, q = lane >> 4;

    float bv[25];
#pragma unroll
    for (int ct = 0; ct < 25; ++ct) bv[ct] = bias[ct * 16 + m];

    f32x4 acc[25];
#pragma unroll
    for (int ct = 0; ct < 25; ++ct) acc[ct] = (f32x4){0.f, 0.f, 0.f, 0.f};

    for (int dc = 0; dc < 6; ++dc) {
        if (dc) __syncthreads();             // protect previous chunk's readers
#pragma unroll
        for (int r = 0; r < 7; ++r) {
            int i = t + r * 256;
            if (i < 1600) {                  // 400 rows x 4 uint4 (32 bf16 = 64B)
                int k = i >> 2, u4 = i & 3;
                uint4 v = *(const uint4*)(Wt + (size_t)k * DIM + dc * 32 + u4 * 8);
                *(uint4*)(wsh + k * 20 + u4 * 4) = v;
            }
        }
        __syncthreads();

        const unsigned short* xp = (const unsigned short*)xs
                                   + (16 * w + m) * 200 + dc * 32 + q * 8;
        bf16x8 af = *(const bf16x8*)xp;
#pragma unroll
        for (int ct = 0; ct < 25; ++ct) {
            const unsigned short* bp = (const unsigned short*)wsh
                                       + (ct * 16 + m) * 40 + q * 8;
            bf16x8 bf = *(const bf16x8*)bp;
            acc[ct] = __builtin_amdgcn_mfma_f32_16x16x32_bf16(af, bf, acc[ct], 0, 0, 0);
        }
    }

    _Float16* __restrict__ pb = preh + (size_t)b * G4 * chunk + (size_t)sblk * 64
                                + 16 * w + q * 4;
#pragma unroll
    for (int ct = 0; ct < 25; ++ct) {
        f16x4 v;
        v[0] = (_Float16)(acc[ct][0] + bv[ct]);
        v[1] = (_Float16)(acc[ct][1] + bv[ct]);
        v[2] = (_Float16)(acc[ct][2] + bv[ct]);
        v[3] = (_Float16)(acc[ct][3] + bv[ct]);
        *(f16x4*)(pb + (size_t)(ct * 16 + m) * chunk) = v;
    }
}

// ---------------------------------------------------------------------------
// Kernel 2 (round-12/13): LSTM scan, 256 thr (4 waves = 1/SIMD) per batch b.
//   Thread (n = t>>1, p = t&1): ALL 4 gates of unit n over j-half p
//   (26 pairs, 104 dot2, split 13+13 chains). XOR-ordered U fragments ->
//   pair-reduce = 2 DPP + 2 add; activations split across the pair
//   (p0: i,f; p1: g,o); gate exchange = 2 DPP; c/h valid on p0.
//   r13: hp extraction fully unrolled with LITERAL shufflevector indices
//   (r12 compile error: indices must be constant integers).
// ---------------------------------------------------------------------------
__global__ __launch_bounds__(256)
void lstm_scan(const _Float16* __restrict__ preh, const half2_t* __restrict__ Ut2b,
               const float* __restrict__ Wd, const float* __restrict__ bd,
               float* __restrict__ out, float* __restrict__ state,
               int nsteps, int first, int last)
{
    __shared__ __align__(16) _Float16 h2[2][112];  // halves: [0..51], [56..107]
    __shared__ __align__(16) float hf32[HID];

    const int b  = blockIdx.x;
    const int t  = threadIdx.x;
    const int p  = t & 1;
    const int nr = t >> 1;                   // 0..127
    const int n  = (nr < HID) ? nr : HID - 1;
    const bool active = (nr < HID);
    const int slot = (n < 52) ? n : (56 + n - 52);

    // Uc[gi][r]: gate order [2p, 2p+1, 2-2p, 3-2p], j-half p (26 pairs)
    half2_t Uc[4][26];
#pragma unroll
    for (int gi = 0; gi < 4; ++gi) {
        const half2_t* up = Ut2b + (size_t)((n * 2 + p) * 4 + gi) * 26;
#pragma unroll
        for (int r = 0; r < 26; ++r) Uc[gi][r] = up[r];
    }

    if (t < 224) ((_Float16*)h2)[t] = (_Float16)0.f;
    float c;
    if (first) {
        c = 0.f;
        __syncthreads();
    } else {
        c = state[BATCH * HID + b * HID + n];     // used on p0 only
        __syncthreads();                          // zeros visible
        if (t < HID) h2[0][(t < 52) ? t : (56 + t - 52)] = (_Float16)state[b * HID + t];
        __syncthreads();
    }

    // two z streams: gates 2p and 2p+1 of unit n, contiguous in s
    const _Float16* __restrict__ zpA = preh + ((size_t)b * G4 + (2 * p)     * HID + n) * nsteps;
    const _Float16* __restrict__ zpB = preh + ((size_t)b * G4 + (2 * p + 1) * HID + n) * nsteps;

    // p0: vA = sigmoid (i);  p1: vA = tanh (g).  vB always sigmoid (f / o).
    const float scaleA = p ? -LOG2E2 : -LOG2E;
    const float AactA  = p ? 2.0f : 1.0f;
    const float BactA  = p ? -1.0f : 0.0f;

    float hn_last = 0.f;

    auto step = [&](float zAk, float zBk, int cur) {
        const _Float16* hb = &h2[cur][p * 56];
        f16x8  g0 = *(const f16x8*)(hb);
        f16x8  g1 = *(const f16x8*)(hb + 8);
        f16x8  g2 = *(const f16x8*)(hb + 16);
        f16x8  g3 = *(const f16x8*)(hb + 24);
        f16x8  g4 = *(const f16x8*)(hb + 32);
        f16x8  g5 = *(const f16x8*)(hb + 40);
        f16x4  g6 = *(const f16x4*)(hb + 48);
        half2_t hp[26];
        hp[0]  = __builtin_shufflevector(g0, g0, 0, 1);
        hp[1]  = __builtin_shufflevector(g0, g0, 2, 3);
        hp[2]  = __builtin_shufflevector(g0, g0, 4, 5);
        hp[3]  = __builtin_shufflevector(g0, g0, 6, 7);
        hp[4]  = __builtin_shufflevector(g1, g1, 0, 1);
        hp[5]  = __builtin_shufflevector(g1, g1, 2, 3);
        hp[6]  = __builtin_shufflevector(g1, g1, 4, 5);
        hp[7]  = __builtin_shufflevector(g1, g1, 6, 7);
        hp[8]  = __builtin_shufflevector(g2, g2, 0, 1);
        hp[9]  = __builtin_shufflevector(g2, g2, 2, 3);
        hp[10] = __builtin_shufflevector(g2, g2, 4, 5);
        hp[11] = __builtin_shufflevector(g2, g2, 6, 7);
        hp[12] = __builtin_shufflevector(g3, g3, 0, 1);
        hp[13] = __builtin_shufflevector(g3, g3, 2, 3);
        hp[14] = __builtin_shufflevector(g3, g3, 4, 5);
        hp[15] = __builtin_shufflevector(g3, g3, 6, 7);
        hp[16] = __builtin_shufflevector(g4, g4, 0, 1);
        hp[17] = __builtin_shufflevector(g4, g4, 2, 3);
        hp[18] = __builtin_shufflevector(g4, g4, 4, 5);
        hp[19] = __builtin_shufflevector(g4, g4, 6, 7);
        hp[20] = __builtin_shufflevector(g5, g5, 0, 1);
        hp[21] = __builtin_shufflevector(g5, g5, 2, 3);
        hp[22] = __builtin_shufflevector(g5, g5, 4, 5);
        hp[23] = __builtin_shufflevector(g5, g5, 6, 7);
        hp[24] = __builtin_shufflevector(g6, g6, 0, 1);
        hp[25] = __builtin_shufflevector(g6, g6, 2, 3);

        float qa0 = 0.f, qa1 = 0.f, qa2 = 0.f, qa3 = 0.f;   // chains r 0..12
        float qb0 = 0.f, qb1 = 0.f, qb2 = 0.f, qb3 = 0.f;   // chains r 13..25
#pragma unroll
        for (int r = 0; r < 13; ++r) {
            qa0 = __builtin_amdgcn_fdot2(Uc[0][r], hp[r], qa0, false);
            qa1 = __builtin_amdgcn_fdot2(Uc[1][r], hp[r], qa1, false);
            qa2 = __builtin_amdgcn_fdot2(Uc[2][r], hp[r], qa2, false);
            qa3 = __builtin_amdgcn_fdot2(Uc[3][r], hp[r], qa3, false);
        }
#pragma unroll
        for (int r = 13; r < 26; ++r) {
            qb0 = __builtin_amdgcn_fdot2(Uc[0][r], hp[r], qb0, false);
            qb1 = __builtin_amdgcn_fdot2(Uc[1][r], hp[r], qb1, false);
            qb2 = __builtin_amdgcn_fdot2(Uc[2][r], hp[r], qb2, false);
            qb3 = __builtin_amdgcn_fdot2(Uc[3][r], hp[r], qb3, false);
        }
        float a0 = qa0 + qb0;                // gate 2p,   half p
        float a1 = qa1 + qb1;                // gate 2p+1, half p
        float a2 = qa2 + qb2;                // gate 2-2p, half p
        float a3 = qa3 + qb3;                // gate 3-2p, half p

        // pair reduce: partner's a2 = my gate 2p, other half; same for a3
        float aA = a0 + fdpp<DPP_X1>(a2) + zAk;
        float aB = a1 + fdpp<DPP_X1>(a3) + zBk;

        float vA = fmaf(AactA,
                        __builtin_amdgcn_rcpf(1.0f + __builtin_amdgcn_exp2f(scaleA * aA)),
                        BactA);                               // i (p0) / g (p1)
        float vB = __builtin_amdgcn_rcpf(1.0f + __builtin_amdgcn_exp2f(-LOG2E * aB));
                                                              // f (p0) / o (p1)
        float gA = fdpp<DPP_X1>(vA);         // on p0: g
        float gB = fdpp<DPP_X1>(vB);         // on p0: o

        c = fmaf(vB, c, vA * gA);            // f*c + i*g   (valid on p0)
        float tc = fmaf(2.0f,
                        __builtin_amdgcn_rcpf(1.0f + __builtin_amdgcn_exp2f(-LOG2E2 * c)),
                        -1.0f);
        float hn = gB * tc;                  // o * tanh(c) (valid on p0)
        if (p == 0 && active) h2[cur ^ 1][slot] = (_Float16)hn;
        hn_last = hn;
        __syncthreads();
    };

    for (int s8 = 0; s8 < nsteps; s8 += 8) {     // nsteps % 8 == 0
        f16x8 zva = *(const f16x8*)(zpA + s8);
        f16x8 zvb = *(const f16x8*)(zpB + s8);
#pragma unroll
        for (int k = 0; k < 8; ++k)
            step((float)zva[k], (float)zvb[k], k & 1);
    }

    if (last) {
        if (p == 0 && active) hf32[n] = hn_last;
        __syncthreads();
        if (t < NCLS) {
            float acc2 = bd[t];
            const float4* h4 = (const float4*)hf32;
#pragma unroll 5
            for (int j4 = 0; j4 < 25; ++j4) {
                float4 hv = h4[j4];
                acc2 = fmaf(hv.x, Wd[(size_t)(4 * j4 + 0) * NCLS + t], acc2);
                acc2 = fmaf(hv.y, Wd[(size_t)(4 * j4 + 1) * NCLS + t], acc2);
                acc2 = fmaf(hv.z, Wd[(size_t)(4 * j4 + 2) * NCLS + t], acc2);
                acc2 = fmaf(hv.w, Wd[(size_t)(4 * j4 + 3) * NCLS + t], acc2);
            }
            out[(size_t)b * NCLS + t] = acc2;
        }
    } else {
        if (p == 0 && active) {
            state[b * HID + n] = hn_last;
            state[BATCH * HID + b * HID + n] = c;
        }
    }
}

// ---------------------------------------------------------------------------
extern "C" void kernel_launch(void* const* d_in, const int* in_sizes, int n_in,
                              void* d_out, int out_size, void* d_ws, size_t ws_size,
                              hipStream_t stream)
{
    const float* x    = (const float*)d_in[0];
    const float* W    = (const float*)d_in[1];
    const float* U    = (const float*)d_in[2];
    const float* bias = (const float*)d_in[3];
    const float* Wd   = (const float*)d_in[4];
    const float* bd   = (const float*)d_in[5];
    float* out = (float*)d_out;

    // ws (dwords): [state 51200][Ut2b 20800][Wt_bf 38400][preh f16: chunk*51200 dw]
    const size_t fixed_dw = 51200 + 20800 + 38400;   // 110400
    int chunk = 64;
    if      (ws_size >= (fixed_dw + (size_t)384 * 51200) * 4) chunk = 384;
    else if (ws_size >= (fixed_dw + (size_t)192 * 51200) * 4) chunk = 192;
    const int nchunks = S_LEN / chunk;

    unsigned int* wsb = (unsigned int*)d_ws;
    float*          state = (float*)wsb;
    half2_t*        Ut2b  = (half2_t*)(wsb + 51200);
    unsigned short* Wt    = (unsigned short*)(wsb + 72000);
    _Float16*       preh  = (_Float16*)(wsb + 110400);

    prep<<<382, 256, 0, stream>>>(W, U, Wt, Ut2b);

    for (int ci = 0; ci < nchunks; ++ci) {
        const int s0 = ci * chunk;
        gemm_pre<<<BATCH * (chunk >> 6), 256, 0, stream>>>(x, Wt, bias, preh, s0, chunk);
        lstm_scan<<<BATCH, 256, 0, stream>>>(preh, Ut2b, Wd, bd, out, state,
                                             chunk, ci == 0 ? 1 : 0,
                                             ci == nchunks - 1 ? 1 : 0);
    }
}